// Round 7
// baseline (169.083 us; speedup 1.0000x reference)
//
#include <hip/hip_runtime.h>
#include <float.h>

// Problem constants (from reference setup_inputs)
#define NS   16384   // samples
#define K1   512     // d_in
#define F    256     // n_feat
#define NC   1000    // n_classes
#define SPB  32      // samples per block
#define NTHR 512     // 8 waves
#define NBLK (NS / SPB)

// f16 split-precision MFMA plan:
//   value = hi + lo, hi = f16(v), lo = f16(v - hi)  => 2^-22 relative capture.
//   A*B ~= Ah*Bh + Ah*Bl + Al*Bh  (ll term ~2^-22 rel, dropped).
//   Pre-scale x*8, W*16, means*16: keeps lo terms f16-normal (flush-proof),
//   argmax-invariant (positive scales). Verified round 6: absmax 0.
// MFMA 16x16x32 f16 layouts (HW-verified m89/m91/m120):
//   A[m][k]: m=lane&15, k=(lane>>4)*8+j
//   B[k][n]: n=lane&15, k=(lane>>4)*8+j
//   C/D:     col=lane&15, row=(lane>>4)*4+reg
// Tie-break: reference argmin takes FIRST min => lowest class index wins.

typedef _Float16 half8 __attribute__((ext_vector_type(8)));
typedef _Float16 half4 __attribute__((ext_vector_type(4)));
typedef float    float4v __attribute__((ext_vector_type(4)));

// Workspace (halves): Wh 131072 | Wl 131072 | Mh 262144 | Ml 262144
#define WH_OFF 0
#define WL_OFF 131072
#define MH_OFF 262144
#define ML_OFF (262144 + 262144)

// ---- merged prep: W and means -> swizzled f16 hi/lo fragments ----
__global__ void prep_frags(const float* __restrict__ W,
                           const float* __restrict__ means,
                           _Float16* __restrict__ ws) {
    int g = blockIdx.x * blockDim.x + threadIdx.x;   // 0..49151
    if (g < 16384) {                                  // W: tile = ks*16+nt
        int lane = g & 63, tile = g >> 6;
        int ks = tile >> 4, nt = tile & 15;
        int k0 = ks * 32 + (lane >> 4) * 8;
        int n  = nt * 16 + (lane & 15);
        _Float16* dh = ws + WH_OFF + (size_t)g * 8;
        _Float16* dl = ws + WL_OFF + (size_t)g * 8;
#pragma unroll
        for (int j = 0; j < 8; ++j) {
            float v = W[(size_t)(k0 + j) * F + n] * 16.0f;
            _Float16 hi = (_Float16)v;
            dh[j] = hi;
            dl[j] = (_Float16)(v - (float)hi);
        }
    } else {                                          // means: tile = ks*64+gt
        int gm = g - 16384;
        int lane = gm & 63, tile = gm >> 6;
        int ks = tile >> 6, gt = tile & 63;
        int k0 = ks * 32 + (lane >> 4) * 8;
        int c  = gt * 16 + (lane & 15);
        _Float16* dh = ws + MH_OFF + (size_t)gm * 8;
        _Float16* dl = ws + ML_OFF + (size_t)gm * 8;
#pragma unroll
        for (int j = 0; j < 8; ++j) {
            float v = (c < NC) ? means[(size_t)c * F + k0 + j] * 16.0f : 0.0f;
            _Float16 hi = (_Float16)v;
            dh[j] = hi;
            dl[j] = (_Float16)(v - (float)hi);
        }
    }
}

#define MFMA(a, b, c) __builtin_amdgcn_mfma_f32_16x16x32_f16((a), (b), (c), 0, 0, 0)

// LDS 52224 B -> 3 blocks/CU (24 waves/CU, 6/EU). No waves/EU max cap.
__attribute__((amdgpu_flat_work_group_size(NTHR, NTHR), amdgpu_waves_per_eu(2, 8)))
__global__ void fused_mfma(const float* __restrict__ x,
                           const _Float16* __restrict__ ws,
                           float* __restrict__ out) {
    // Manual union: cand/bidx overlap the xs region (xs dead by merge time).
    __shared__ __align__(16) unsigned char smem[52224];
    _Float16 (*xsh)[32][72] = reinterpret_cast<_Float16 (*)[32][72]>(smem);          // [2][32][72] hi
    _Float16 (*xsl)[32][72] = reinterpret_cast<_Float16 (*)[32][72]>(smem + 9216);   // lo
    _Float16 (*fh)[264]     = reinterpret_cast<_Float16 (*)[264]>(smem + 18432);     // [32][264]
    _Float16 (*fl)[264]     = reinterpret_cast<_Float16 (*)[264]>(smem + 35328);
    float (*cand_v)[8]      = reinterpret_cast<float (*)[8]>(smem);                  // 32x8
    int   (*cand_i)[8]      = reinterpret_cast<int (*)[8]>(smem + 1024);
    int*  bidx              = reinterpret_cast<int*>(smem + 2048);

    const int tid  = threadIdx.x;
    const int lane = tid & 63;
    const int w    = tid >> 6;    // wave 0..7
    const int quad = lane >> 4;   // 0..3
    const int cl   = lane & 15;
    const int s0   = blockIdx.x * SPB;

    // staging coords: 512 threads cover 32 rows x 64 cols (float4 each)
    const int xrow = tid >> 4;          // 0..31
    const int xc4  = (tid & 15) * 4;    // 0,4,..,60

    // ===== Phase 1: feats = (8x) @ (16W), f16-split MFMA, KC=64 chunks =====
    float4v acc1[2][2];   // [p][mt]
#pragma unroll
    for (int p = 0; p < 2; ++p)
#pragma unroll
        for (int mt = 0; mt < 2; ++mt)
            acc1[p][mt] = (float4v){0.f, 0.f, 0.f, 0.f};

    float4 xv = *reinterpret_cast<const float4*>(x + (size_t)(s0 + xrow) * K1 + xc4);

    for (int ks8 = 0; ks8 < 8; ++ks8) {
        const int buf = ks8 & 1;
        {   // convert (scale x8) and stage as hi/lo half4
            float v0 = xv.x * 8.0f, v1 = xv.y * 8.0f, v2 = xv.z * 8.0f, v3 = xv.w * 8.0f;
            _Float16 h0 = (_Float16)v0, h1 = (_Float16)v1, h2 = (_Float16)v2, h3 = (_Float16)v3;
            *reinterpret_cast<half4*>(&xsh[buf][xrow][xc4]) = (half4){h0, h1, h2, h3};
            *reinterpret_cast<half4*>(&xsl[buf][xrow][xc4]) =
                (half4){(_Float16)(v0 - (float)h0), (_Float16)(v1 - (float)h1),
                        (_Float16)(v2 - (float)h2), (_Float16)(v3 - (float)h3)};
        }
        __syncthreads();   // one barrier per 64-wide chunk (ping-pong)
        if (ks8 < 7)
            xv = *reinterpret_cast<const float4*>(
                x + (size_t)(s0 + xrow) * K1 + (ks8 + 1) * 64 + xc4);

#pragma unroll
        for (int s2 = 0; s2 < 2; ++s2) {       // two K=32 MFMA steps per chunk
            const int ks = ks8 * 2 + s2;
            half8 ah[2], al[2];
#pragma unroll
            for (int mt = 0; mt < 2; ++mt) {
                ah[mt] = *reinterpret_cast<const half8*>(
                    &xsh[buf][mt * 16 + cl][s2 * 32 + quad * 8]);
                al[mt] = *reinterpret_cast<const half8*>(
                    &xsl[buf][mt * 16 + cl][s2 * 32 + quad * 8]);
            }
#pragma unroll
            for (int p = 0; p < 2; ++p) {
                const int tile = ks * 16 + (w * 2 + p);
                half8 bh = *reinterpret_cast<const half8*>(
                    ws + WH_OFF + ((size_t)tile * 64 + lane) * 8);
                half8 bl = *reinterpret_cast<const half8*>(
                    ws + WL_OFF + ((size_t)tile * 64 + lane) * 8);
#pragma unroll
                for (int mt = 0; mt < 2; ++mt) {
                    acc1[p][mt] = MFMA(ah[mt], bh, acc1[p][mt]);
                    acc1[p][mt] = MFMA(ah[mt], bl, acc1[p][mt]);
                    acc1[p][mt] = MFMA(al[mt], bh, acc1[p][mt]);
                }
            }
        }
        // no trailing barrier: next iter writes the other buffer
    }

    // park feats (scaled x128) into LDS as f16 hi/lo
#pragma unroll
    for (int p = 0; p < 2; ++p)
#pragma unroll
        for (int mt = 0; mt < 2; ++mt)
#pragma unroll
            for (int r = 0; r < 4; ++r) {
                int srow = mt * 16 + quad * 4 + r;
                int n    = (w * 2 + p) * 16 + cl;
                float v  = acc1[p][mt][r];
                _Float16 hi = (_Float16)v;
                fh[srow][n] = hi;
                fl[srow][n] = (_Float16)(v - (float)hi);
            }
    __syncthreads();

    // ===== Phase 2: scores = feats @ means.T, software-pipelined =====
    // Wave w owns class tiles w*8..w*8+7 (classes w*128..+127) for both M-tiles.
    float4v acc2[2][8];   // [mt][nt]
#pragma unroll
    for (int mt = 0; mt < 2; ++mt)
#pragma unroll
        for (int nt = 0; nt < 8; ++nt)
            acc2[mt][nt] = (float4v){0.f, 0.f, 0.f, 0.f};

    const _Float16* mhb = ws + MH_OFF + (size_t)(w * 8) * 64 * 8 + (size_t)lane * 8;
    const _Float16* mlb = ws + ML_OFF + (size_t)(w * 8) * 64 * 8 + (size_t)lane * 8;
    // tile(ks,nt) byte-base offset: (ks*64 + nt)*64*8 halves from mhb

    half8 fahC[2], falC[2], fahN[2], falN[2];
#pragma unroll
    for (int mt = 0; mt < 2; ++mt) {   // A-frags for ks=0
        fahC[mt] = *reinterpret_cast<const half8*>(&fh[mt * 16 + cl][quad * 8]);
        falC[mt] = *reinterpret_cast<const half8*>(&fl[mt * 16 + cl][quad * 8]);
    }
    half8 cmh = *reinterpret_cast<const half8*>(mhb);   // B-frag (ks=0, nt=0)
    half8 cml = *reinterpret_cast<const half8*>(mlb);

    for (int ks = 0; ks < 8; ++ks) {
        if (ks < 7) {   // prefetch next-ks A-frags a whole ks ahead
#pragma unroll
            for (int mt = 0; mt < 2; ++mt) {
                fahN[mt] = *reinterpret_cast<const half8*>(
                    &fh[mt * 16 + cl][(ks + 1) * 32 + quad * 8]);
                falN[mt] = *reinterpret_cast<const half8*>(
                    &fl[mt * 16 + cl][(ks + 1) * 32 + quad * 8]);
            }
        }
#pragma unroll
        for (int nt = 0; nt < 8; ++nt) {
            // prefetch next B-frag (1 step ahead; clamp at the very end)
            const int t  = ks * 8 + nt;
            const int tn = (t + 1 < 64) ? t + 1 : 63;
            const size_t noff = (size_t)(((tn >> 3) * 64 + (tn & 7)) * 64) * 8;
            half8 nmh = *reinterpret_cast<const half8*>(mhb + noff);
            half8 nml = *reinterpret_cast<const half8*>(mlb + noff);
#pragma unroll
            for (int mt = 0; mt < 2; ++mt) {
                acc2[mt][nt] = MFMA(fahC[mt], cmh, acc2[mt][nt]);
                acc2[mt][nt] = MFMA(fahC[mt], cml, acc2[mt][nt]);
                acc2[mt][nt] = MFMA(falC[mt], cmh, acc2[mt][nt]);
            }
            cmh = nmh; cml = nml;
        }
#pragma unroll
        for (int mt = 0; mt < 2; ++mt) { fahC[mt] = fahN[mt]; falC[mt] = falN[mt]; }
    }

    // ---- argmax from C/D layout: row=quad*4+r, col=cl ----
#pragma unroll
    for (int mt = 0; mt < 2; ++mt)
#pragma unroll
        for (int r = 0; r < 4; ++r) {
            float v  = -FLT_MAX;
            int   ix = 0x7FFFFFFF;
#pragma unroll
            for (int nt = 0; nt < 8; ++nt) {          // ascending class order
                int c = (w * 8 + nt) * 16 + cl;
                if (c < NC) {
                    float sc = acc2[mt][nt][r];
                    if (sc > v) { v = sc; ix = c; }   // strict >: lowest wins
                }
            }
#pragma unroll
            for (int off = 1; off < 16; off <<= 1) {  // merge 16 lanes of quad
                float ov = __shfl_xor(v, off, 64);
                int   oi = __shfl_xor(ix, off, 64);
                if (ov > v || (ov == v && oi < ix)) { v = ov; ix = oi; }
            }
            if (cl == 0) {
                int srow = mt * 16 + quad * 4 + r;
                cand_v[srow][w] = v;
                cand_i[srow][w] = ix;
            }
        }
    __syncthreads();

    if (tid < 32) {   // merge 8 wave-candidates (ascending class ranges)
        float v  = cand_v[tid][0];
        int   ix = cand_i[tid][0];
#pragma unroll
        for (int q = 1; q < 8; ++q) {
            float ov = cand_v[tid][q];
            int   oi = cand_i[tid][q];
            if (ov > v || (ov == v && oi < ix)) { v = ov; ix = oi; }
        }
        bidx[tid] = ix;
    }
    __syncthreads();

    // ================= Epilogue: write one-hot rows =================
    const int NF4 = NC / 4;  // 250 float4 per row
    for (int q = tid; q < SPB * NF4; q += NTHR) {
        int row   = q / NF4;
        int c4    = q - row * NF4;
        int b     = bidx[row];
        int cbase = c4 * 4;
        float4 v;
        v.x = (cbase + 0 == b) ? 1.f : 0.f;
        v.y = (cbase + 1 == b) ? 1.f : 0.f;
        v.z = (cbase + 2 == b) ? 1.f : 0.f;
        v.w = (cbase + 3 == b) ? 1.f : 0.f;
        *reinterpret_cast<float4*>(out + (size_t)(s0 + row) * NC + cbase) = v;
    }
}

extern "C" void kernel_launch(void* const* d_in, const int* in_sizes, int n_in,
                              void* d_out, int out_size, void* d_ws, size_t ws_size,
                              hipStream_t stream) {
    const float* x     = (const float*)d_in[0];
    const float* W     = (const float*)d_in[1];
    const float* means = (const float*)d_in[2];
    float* out         = (float*)d_out;
    _Float16* ws       = (_Float16*)d_ws;   // 1.5 MB of swizzled f16 fragments

    prep_frags<<<192, 256, 0, stream>>>(W, means, ws);
    fused_mfma<<<NBLK, NTHR, 0, stream>>>(x, ws, out);
}

// Round 8
// 155.041 us; speedup vs baseline: 1.0906x; 1.0906x over previous
//
#include <hip/hip_runtime.h>
#include <float.h>

// Problem constants (from reference setup_inputs)
#define NS   16384   // samples
#define K1   512     // d_in
#define F    256     // n_feat
#define NC   1000    // n_classes
#define SPB  32      // samples per block
#define NTHR 512     // 8 waves
#define NBLK (NS / SPB)

// f16 split-precision MFMA plan (verified round 6, absmax 0):
//   value = hi + lo, hi = f16(v), lo = f16(v - hi)  => 2^-22 relative capture.
//   A*B ~= Ah*Bh + Ah*Bl + Al*Bh  (ll term ~2^-22 rel, dropped).
//   Pre-scale x*8, W*16, means*16: keeps lo terms f16-normal (flush-proof),
//   argmax-invariant (positive scales).
// MFMA 16x16x32 f16 layouts (HW-verified m89/m91/m120):
//   A[m][k]: m=lane&15, k=(lane>>4)*8+j
//   B[k][n]: n=lane&15, k=(lane>>4)*8+j
//   C/D:     col=lane&15, row=(lane>>4)*4+reg
// Tie-break: reference argmin takes FIRST min => lowest class index wins.
//
// Round-8 notes: round 7's manual pipeline (register rotation) serialized
// loads behind MFMAs and regressed 63->93 us. This file is the round-6
// structure with only: (a) merged prep kernel, (b) hi/lo frags interleaved
// per tile (one base address), (c) nt-pair load batching in phase 2.

typedef _Float16 half8 __attribute__((ext_vector_type(8)));
typedef float    float4v __attribute__((ext_vector_type(4)));

// Workspace (halves): W tiles [0,256): hi at t*1024, lo at t*1024+512.
// Means tiles [0,512) at MOFF + t*1024 (+512 for lo).
#define MOFF 262144

// ---- merged prep: W and means -> swizzled f16 hi/lo fragments ----
__global__ void prep_frags(const float* __restrict__ W,
                           const float* __restrict__ means,
                           _Float16* __restrict__ ws) {
    int g = blockIdx.x * blockDim.x + threadIdx.x;   // 0..49151
    if (g < 16384) {                                  // W: tile = ks*16+nt
        int lane = g & 63, tile = g >> 6;
        int ks = tile >> 4, nt = tile & 15;
        int k0 = ks * 32 + (lane >> 4) * 8;
        int n  = nt * 16 + (lane & 15);
        _Float16* dh = ws + (size_t)tile * 1024 + lane * 8;
#pragma unroll
        for (int j = 0; j < 8; ++j) {
            float v = W[(size_t)(k0 + j) * F + n] * 16.0f;
            _Float16 hi = (_Float16)v;
            dh[j]       = hi;
            dh[512 + j] = (_Float16)(v - (float)hi);
        }
    } else {                                          // means: tile = ks*64+gt
        int gm = g - 16384;
        int lane = gm & 63, tile = gm >> 6;
        int ks = tile >> 6, gt = tile & 63;
        int k0 = ks * 32 + (lane >> 4) * 8;
        int c  = gt * 16 + (lane & 15);
        _Float16* dh = ws + MOFF + (size_t)tile * 1024 + lane * 8;
#pragma unroll
        for (int j = 0; j < 8; ++j) {
            float v = (c < NC) ? means[(size_t)c * F + k0 + j] * 16.0f : 0.0f;
            _Float16 hi = (_Float16)v;
            dh[j]       = hi;
            dh[512 + j] = (_Float16)(v - (float)hi);
        }
    }
}

#define MFMA(a, b, c) __builtin_amdgcn_mfma_f32_16x16x32_f16((a), (b), (c), 0, 0, 0)

// Round-6 config: LDS 47616 B, waves_per_eu(2,4) -> 2 blocks/CU, 16 waves/CU.
__attribute__((amdgpu_flat_work_group_size(NTHR, NTHR), amdgpu_waves_per_eu(2, 4)))
__global__ void fused_mfma(const float* __restrict__ x,
                           const _Float16* __restrict__ ws,
                           float* __restrict__ out) {
    __shared__ _Float16 xsh[2][32][44];   // x chunk hi, ping-pong, padded stride
    __shared__ _Float16 xsl[2][32][44];   // x chunk lo
    __shared__ _Float16 fh[32][264];      // feats hi (scaled x128), padded stride
    __shared__ _Float16 fl[32][264];      // feats lo
    __shared__ float cand_v[32][8];
    __shared__ int   cand_i[32][8];
    __shared__ int   bidx[32];

    const int tid  = threadIdx.x;
    const int lane = tid & 63;
    const int w    = tid >> 6;    // wave 0..7
    const int quad = lane >> 4;   // 0..3
    const int cl   = lane & 15;
    const int s0   = blockIdx.x * SPB;

    // staging coords: 512 threads cover 32 rows x 32 cols (2 floats each)
    const int xrow = tid >> 4;          // 0..31
    const int xc   = (tid & 15) * 2;    // 0,2,..,30

    // ================= Phase 1: feats = (8x) @ (16W), f16-split MFMA ========
    float4v acc1[2][2];   // [p = n-subtile][mt]
#pragma unroll
    for (int p = 0; p < 2; ++p)
#pragma unroll
        for (int mt = 0; mt < 2; ++mt)
            acc1[p][mt] = (float4v){0.f, 0.f, 0.f, 0.f};

    float2 xv = *reinterpret_cast<const float2*>(x + (size_t)(s0 + xrow) * K1 + xc);

    for (int ks = 0; ks < 16; ++ks) {
        const int buf = ks & 1;
        {   // convert (scale x8) and stage
            float vx = xv.x * 8.0f, vy = xv.y * 8.0f;
            _Float16 hx = (_Float16)vx, hy = (_Float16)vy;
            xsh[buf][xrow][xc]     = hx;
            xsh[buf][xrow][xc + 1] = hy;
            xsl[buf][xrow][xc]     = (_Float16)(vx - (float)hx);
            xsl[buf][xrow][xc + 1] = (_Float16)(vy - (float)hy);
        }
        __syncthreads();
        if (ks < 15)
            xv = *reinterpret_cast<const float2*>(
                x + (size_t)(s0 + xrow) * K1 + (ks + 1) * 32 + xc);

        half8 ah[2], al[2];
#pragma unroll
        for (int mt = 0; mt < 2; ++mt) {
            ah[mt] = *reinterpret_cast<const half8*>(&xsh[buf][mt * 16 + cl][quad * 8]);
            al[mt] = *reinterpret_cast<const half8*>(&xsl[buf][mt * 16 + cl][quad * 8]);
        }
#pragma unroll
        for (int p = 0; p < 2; ++p) {
            const int tile = ks * 16 + (w * 2 + p);
            const _Float16* wb = ws + (size_t)tile * 1024 + lane * 8;
            half8 bh = *reinterpret_cast<const half8*>(wb);
            half8 bl = *reinterpret_cast<const half8*>(wb + 512);
#pragma unroll
            for (int mt = 0; mt < 2; ++mt) {
                acc1[p][mt] = MFMA(ah[mt], bh, acc1[p][mt]);
                acc1[p][mt] = MFMA(ah[mt], bl, acc1[p][mt]);
                acc1[p][mt] = MFMA(al[mt], bh, acc1[p][mt]);
            }
        }
        // no trailing barrier: next iter writes the other buffer
    }

    // park feats (scaled x128) into LDS as f16 hi/lo
#pragma unroll
    for (int p = 0; p < 2; ++p)
#pragma unroll
        for (int mt = 0; mt < 2; ++mt)
#pragma unroll
            for (int r = 0; r < 4; ++r) {
                int srow = mt * 16 + quad * 4 + r;
                int n    = (w * 2 + p) * 16 + cl;
                float v  = acc1[p][mt][r];
                _Float16 hi = (_Float16)v;
                fh[srow][n] = hi;
                fl[srow][n] = (_Float16)(v - (float)hi);
            }
    __syncthreads();

    // ========== Phase 2: scores = feats @ means.T, f16-split MFMA ==========
    // Wave w owns class tiles w*8..w*8+7 (classes w*128..+127) for both M-tiles.
    // nt-pair batching: 4 independent loads, then 12 MFMAs (no reg rotation).
    float4v acc2[2][8];   // [mt][nt]
#pragma unroll
    for (int mt = 0; mt < 2; ++mt)
#pragma unroll
        for (int nt = 0; nt < 8; ++nt)
            acc2[mt][nt] = (float4v){0.f, 0.f, 0.f, 0.f};

    for (int ks = 0; ks < 8; ++ks) {
        half8 fah[2], fal[2];
#pragma unroll
        for (int mt = 0; mt < 2; ++mt) {
            fah[mt] = *reinterpret_cast<const half8*>(
                &fh[mt * 16 + cl][ks * 32 + quad * 8]);
            fal[mt] = *reinterpret_cast<const half8*>(
                &fl[mt * 16 + cl][ks * 32 + quad * 8]);
        }
#pragma unroll
        for (int nt2 = 0; nt2 < 8; nt2 += 2) {
            const int t0 = ks * 64 + (w * 8 + nt2);
            const _Float16* mb0 = ws + MOFF + (size_t)t0 * 1024 + lane * 8;
            half8 mh0 = *reinterpret_cast<const half8*>(mb0);
            half8 ml0 = *reinterpret_cast<const half8*>(mb0 + 512);
            half8 mh1 = *reinterpret_cast<const half8*>(mb0 + 1024);
            half8 ml1 = *reinterpret_cast<const half8*>(mb0 + 1536);
#pragma unroll
            for (int mt = 0; mt < 2; ++mt) {
                acc2[mt][nt2] = MFMA(fah[mt], mh0, acc2[mt][nt2]);
                acc2[mt][nt2] = MFMA(fah[mt], ml0, acc2[mt][nt2]);
                acc2[mt][nt2] = MFMA(fal[mt], mh0, acc2[mt][nt2]);
            }
#pragma unroll
            for (int mt = 0; mt < 2; ++mt) {
                acc2[mt][nt2 + 1] = MFMA(fah[mt], mh1, acc2[mt][nt2 + 1]);
                acc2[mt][nt2 + 1] = MFMA(fah[mt], ml1, acc2[mt][nt2 + 1]);
                acc2[mt][nt2 + 1] = MFMA(fal[mt], mh1, acc2[mt][nt2 + 1]);
            }
        }
    }

    // ---- argmax from C/D layout: row=quad*4+r, col=cl ----
#pragma unroll
    for (int mt = 0; mt < 2; ++mt)
#pragma unroll
        for (int r = 0; r < 4; ++r) {
            float v  = -FLT_MAX;
            int   ix = 0x7FFFFFFF;
#pragma unroll
            for (int nt = 0; nt < 8; ++nt) {          // ascending class order
                int c = (w * 8 + nt) * 16 + cl;
                if (c < NC) {
                    float sc = acc2[mt][nt][r];
                    if (sc > v) { v = sc; ix = c; }   // strict >: lowest wins
                }
            }
#pragma unroll
            for (int off = 1; off < 16; off <<= 1) {  // merge 16 lanes of quad
                float ov = __shfl_xor(v, off, 64);
                int   oi = __shfl_xor(ix, off, 64);
                if (ov > v || (ov == v && oi < ix)) { v = ov; ix = oi; }
            }
            if (cl == 0) {
                int srow = mt * 16 + quad * 4 + r;
                cand_v[srow][w] = v;
                cand_i[srow][w] = ix;
            }
        }
    __syncthreads();

    if (tid < 32) {   // merge 8 wave-candidates (ascending class ranges)
        float v  = cand_v[tid][0];
        int   ix = cand_i[tid][0];
#pragma unroll
        for (int q = 1; q < 8; ++q) {
            float ov = cand_v[tid][q];
            int   oi = cand_i[tid][q];
            if (ov > v || (ov == v && oi < ix)) { v = ov; ix = oi; }
        }
        bidx[tid] = ix;
    }
    __syncthreads();

    // ================= Epilogue: write one-hot rows =================
    const int NF4 = NC / 4;  // 250 float4 per row
    for (int q = tid; q < SPB * NF4; q += NTHR) {
        int row   = q / NF4;
        int c4    = q - row * NF4;
        int b     = bidx[row];
        int cbase = c4 * 4;
        float4 v;
        v.x = (cbase + 0 == b) ? 1.f : 0.f;
        v.y = (cbase + 1 == b) ? 1.f : 0.f;
        v.z = (cbase + 2 == b) ? 1.f : 0.f;
        v.w = (cbase + 3 == b) ? 1.f : 0.f;
        *reinterpret_cast<float4*>(out + (size_t)(s0 + row) * NC + cbase) = v;
    }
}

extern "C" void kernel_launch(void* const* d_in, const int* in_sizes, int n_in,
                              void* d_out, int out_size, void* d_ws, size_t ws_size,
                              hipStream_t stream) {
    const float* x     = (const float*)d_in[0];
    const float* W     = (const float*)d_in[1];
    const float* means = (const float*)d_in[2];
    float* out         = (float*)d_out;
    _Float16* ws       = (_Float16*)d_ws;   // 1.5 MB swizzled f16 fragments

    prep_frags<<<192, 256, 0, stream>>>(W, means, ws);
    fused_mfma<<<NBLK, NTHR, 0, stream>>>(x, ws, out);
}